// Round 3
// baseline (862.217 us; speedup 1.0000x reference)
//
#include <hip/hip_runtime.h>
#include <hip/hip_bf16.h>

#define B_   64
#define S_   2048
#define TRG_ 512
#define K_   1024

typedef short short8 __attribute__((ext_vector_type(8)));
typedef float f32x4  __attribute__((ext_vector_type(4)));
typedef unsigned short us4 __attribute__((ext_vector_type(4)));

__device__ __forceinline__ unsigned short f2bf(float f) {
    union { float f; unsigned int u; } v; v.f = f;
    unsigned int u = v.u;
    unsigned int r = (u + 0x7fffu + ((u >> 16) & 1u)) >> 16;  // RNE
    return (unsigned short)r;
}

// pack 8 fp32 -> 8 bf16 (RNE) via compiler-recognized casts (emits v_cvt_pk_bf16_f32)
__device__ __forceinline__ short8 cvt8(float4 a0, float4 a1) {
    union { __hip_bfloat162 h[4]; short8 v; } u;
    u.h[0] = __float22bfloat162_rn(float2{a0.x, a0.y});
    u.h[1] = __float22bfloat162_rn(float2{a0.z, a0.w});
    u.h[2] = __float22bfloat162_rn(float2{a1.x, a1.y});
    u.h[3] = __float22bfloat162_rn(float2{a1.z, a1.w});
    return u.v;
}

// ---------------- W_en fp32 -> bf16 ----------------
__global__ void wen_convert_kernel(const float* __restrict__ Wen,
                                   unsigned short* __restrict__ Wbf) {
    int idx = blockIdx.x * 256 + threadIdx.x;          // 131072 float4s
    float4 f = ((const float4*)Wen)[idx];
    us4 o = { f2bf(f.x), f2bf(f.y), f2bf(f.z), f2bf(f.w) };
    ((us4*)Wbf)[idx] = o;
}

// ---------------- deproj[b,h] = b_en[h] + sum_t dehy[b,t]*W_de[h,t] ----------------
__global__ void deproj_kernel(const float* __restrict__ dehy,
                              const float* __restrict__ Wde,
                              const float* __restrict__ ben,
                              float* __restrict__ dp) {
    int b = blockIdx.x >> 1;
    int h = ((blockIdx.x & 1) << 8) + threadIdx.x;
    const float4* dv = (const float4*)(dehy + (size_t)b * TRG_);
    const float4* wv = (const float4*)(Wde + (size_t)h * TRG_);
    float s = ben[h];
    #pragma unroll 4
    for (int t = 0; t < TRG_ / 4; ++t) {
        float4 a = dv[t], w = wv[t];
        s += a.x * w.x + a.y * w.y + a.z * w.z + a.w * w.w;
    }
    dp[b * TRG_ + h] = s;
}

// ---------------- fused score GEMM + tanh + w_warp reduce + mask ----------------
// Tile M=64 x N=512(all h) x K=1024. 512 threads = 8 waves, n-partitioned:
// wave w owns h in [w*64, w*64+64) -> 4 fn frags; fm = 4 (64 M-rows); acc 4x4 = 64 VGPR.
// NO LDS staging: A frags direct from global fp32 (8 waves share the same lines -> L1),
// B frags direct from L2-resident bf16 Wbf (16B/lane contiguous). No barriers except a
// drift-limiter s_barrier every 2 K-steps (keeps the 8 waves' A reads L1-coherent).
__global__ __launch_bounds__(512, 4) void score_kernel(
    const float* __restrict__ enhy,
    const unsigned short* __restrict__ Wbf,
    const float* __restrict__ dp,
    const float* __restrict__ past_attn,
    const int* __restrict__ src_mask,
    const float* __restrict__ w_cv,
    const float* __restrict__ w_warp,
    float* __restrict__ out_ee)
{
    __shared__ float red[8][64];     // 2 KB

    const int tid  = threadIdx.x;
    const int lane = tid & 63;
    const int w    = tid >> 6;       // 0..7 (n-slice)
    const int lj   = lane & 15;
    const int lg   = lane >> 4;
    const int m0   = blockIdx.x * 64;
    const int b    = m0 >> 11;
    const int s0   = m0 & 2047;

    f32x4 acc[4][4];
    const f32x4 fz = {0.f, 0.f, 0.f, 0.f};
    #pragma unroll
    for (int i = 0; i < 4; ++i)
        #pragma unroll
        for (int j = 0; j < 4; ++j) acc[i][j] = fz;

    // per-lane base offsets (elements)
    const float* aRow          = enhy + (size_t)(m0 + lj) * K_ + (lg << 3);          // + fm*16*K + kt*32
    const unsigned short* bRow = Wbf + (size_t)((w << 6) + lj) * K_ + (lg << 3);     // + fn*16*K + kt*32

    #pragma unroll 2
    for (int kt = 0; kt < 32; ++kt) {
        const int ko = kt << 5;
        short8 bfr[4];
        #pragma unroll
        for (int fn = 0; fn < 4; ++fn)
            bfr[fn] = *(const short8*)(bRow + (size_t)fn * 16 * K_ + ko);
        #pragma unroll
        for (int fm = 0; fm < 4; ++fm) {
            const float* p = aRow + (size_t)fm * 16 * K_ + ko;
            float4 a0 = *(const float4*)p;
            float4 a1 = *(const float4*)(p + 4);
            short8 af = cvt8(a0, a1);
            #pragma unroll
            for (int fn = 0; fn < 4; ++fn)
                acc[fm][fn] = __builtin_amdgcn_mfma_f32_16x16x32_bf16(af, bfr[fn], acc[fm][fn], 0, 0, 0);
        }
        if ((kt & 1) == 1) __builtin_amdgcn_s_barrier();   // drift limiter, no drain
    }

    // ---- epilogue: v = acc + dep + pa*wcv; tanh; *w_warp; reduce over h ----
    float dep4[4], wcv4[4], wwp4[4];
    #pragma unroll
    for (int fn = 0; fn < 4; ++fn) {
        int h = (w << 6) + (fn << 4) + lj;
        dep4[fn] = dp[b * TRG_ + h];
        wcv4[fn] = w_cv[h];
        wwp4[fn] = w_warp[h];
    }
    #pragma unroll
    for (int fm = 0; fm < 4; ++fm) {
        #pragma unroll
        for (int reg = 0; reg < 4; ++reg) {
            int row = (fm << 4) + (lg << 2) + reg;       // 0..63
            float pa = past_attn[b * S_ + s0 + row];
            float p = 0.f;
            #pragma unroll
            for (int fn = 0; fn < 4; ++fn) {
                float v = acc[fm][fn][reg] + dep4[fn] + pa * wcv4[fn];
                float e = __expf(2.f * v);                       // tanh = 1 - 2/(e^{2v}+1)
                float t = 1.f - 2.f * __builtin_amdgcn_rcpf(e + 1.f);
                p += t * wwp4[fn];
            }
            p += __shfl_xor(p, 1);
            p += __shfl_xor(p, 2);
            p += __shfl_xor(p, 4);
            p += __shfl_xor(p, 8);
            if (lj == 0) red[w][row] = p;
        }
    }
    __syncthreads();
    if (tid < 64) {
        float ee = 0.f;
        #pragma unroll
        for (int ww = 0; ww < 8; ++ww) ee += red[ww][tid];
        int msk = src_mask[m0 + tid];
        if (msk == 0) ee = -1e20f;
        out_ee[m0 + tid] = ee;
    }
}

// ---------------- softmax over S per batch row ----------------
__global__ void softmax_kernel(const float* __restrict__ ee, float* __restrict__ attn) {
    int b = blockIdx.x, tid = threadIdx.x;   // 256 threads
    const float* row = ee + (size_t)b * S_;
    float v[8]; float mx = -3.0e38f;
    #pragma unroll
    for (int i = 0; i < 8; ++i) { v[i] = row[tid + (i << 8)]; mx = fmaxf(mx, v[i]); }
    #pragma unroll
    for (int off = 32; off > 0; off >>= 1) mx = fmaxf(mx, __shfl_xor(mx, off));
    __shared__ float sred[4];
    int w = tid >> 6, lane = tid & 63;
    if (lane == 0) sred[w] = mx;
    __syncthreads();
    mx = fmaxf(fmaxf(sred[0], sred[1]), fmaxf(sred[2], sred[3]));
    float sum = 0.f;
    #pragma unroll
    for (int i = 0; i < 8; ++i) { v[i] = __expf(v[i] - mx); sum += v[i]; }
    #pragma unroll
    for (int off = 32; off > 0; off >>= 1) sum += __shfl_xor(sum, off);
    __syncthreads();
    if (lane == 0) sred[w] = sum;
    __syncthreads();
    sum = sred[0] + sred[1] + sred[2] + sred[3];
    float inv = 1.f / sum;
    float* orow = attn + (size_t)b * S_;
    #pragma unroll
    for (int i = 0; i < 8; ++i) orow[tid + (i << 8)] = v[i] * inv;
}

// ---------------- context: partial over s-chunks (deterministic) ----------------
__global__ void ctx_partial_kernel(const float* __restrict__ attn,
                                   const float* __restrict__ enhy,
                                   float* __restrict__ part) {
    int bx = blockIdx.x;              // 64*32
    int b = bx >> 5, sc = bx & 31;
    int tid = threadIdx.x;            // 256; each thread one float4 of d
    const float4* e4 = (const float4*)(enhy + ((size_t)b * S_ + sc * 64) * K_);
    const float* ar = attn + (size_t)b * S_ + sc * 64;
    float4 acc = {0.f, 0.f, 0.f, 0.f};
    #pragma unroll 8
    for (int s = 0; s < 64; ++s) {
        float a = ar[s];
        float4 ev = e4[(size_t)s * 256 + tid];
        acc.x += a * ev.x; acc.y += a * ev.y; acc.z += a * ev.z; acc.w += a * ev.w;
    }
    ((float4*)part)[(size_t)(sc * 64 + b) * 256 + tid] = acc;
}

__global__ void ctx_reduce_kernel(const float* __restrict__ part, float* __restrict__ outc) {
    int idx = blockIdx.x * 256 + threadIdx.x;   // 65536
    int b = idx >> 10, d = idx & 1023;
    float s = 0.f;
    #pragma unroll
    for (int sc = 0; sc < 32; ++sc) s += part[(size_t)((sc << 6) + b) * 1024 + d];
    outc[idx] = s;
}

extern "C" void kernel_launch(void* const* d_in, const int* in_sizes, int n_in,
                              void* d_out, int out_size, void* d_ws, size_t ws_size,
                              hipStream_t stream) {
    (void)in_sizes; (void)n_in; (void)out_size; (void)ws_size;

    const float* dehy = (const float*)d_in[0];
    const float* enhy = (const float*)d_in[1];
    const float* past = (const float*)d_in[2];
    const int*   mask = (const int*)d_in[3];
    const float* Wen  = (const float*)d_in[4];
    const float* ben  = (const float*)d_in[5];
    const float* Wde  = (const float*)d_in[6];
    const float* wcv  = (const float*)d_in[7];
    const float* wwp  = (const float*)d_in[8];

    float* out      = (float*)d_out;
    float* out_c    = out;                      // 64*1024
    float* out_attn = out + 65536;              // 64*2048
    float* out_ee   = out + 65536 + 131072;     // 64*2048

    char* ws = (char*)d_ws;
    unsigned short* Wbf = (unsigned short*)ws;              // 1 MB
    float* dp   = (float*)(ws + (1 << 20));                 // 128 KB
    float* part = (float*)(ws + (1 << 20) + (1 << 17));     // 8 MB

    wen_convert_kernel<<<512, 256, 0, stream>>>(Wen, Wbf);
    deproj_kernel<<<128, 256, 0, stream>>>(dehy, Wde, ben, dp);
    score_kernel<<<2048, 512, 0, stream>>>(enhy, Wbf, dp, past, mask, wcv, wwp, out_ee);
    softmax_kernel<<<64, 256, 0, stream>>>(out_ee, out_attn);
    ctx_partial_kernel<<<2048, 256, 0, stream>>>(out_attn, enhy, part);
    ctx_reduce_kernel<<<256, 256, 0, stream>>>(part, out_c);
}

// Round 4
// 385.211 us; speedup vs baseline: 2.2383x; 2.2383x over previous
//
#include <hip/hip_runtime.h>
#include <hip/hip_bf16.h>

#define B_   64
#define S_   2048
#define TRG_ 512
#define K_   1024

typedef short short8 __attribute__((ext_vector_type(8)));
typedef float f32x4  __attribute__((ext_vector_type(4)));
typedef unsigned short us4 __attribute__((ext_vector_type(4)));

__device__ __forceinline__ unsigned short f2bf(float f) {
    union { float f; unsigned int u; } v; v.f = f;
    unsigned int u = v.u;
    unsigned int r = (u + 0x7fffu + ((u >> 16) & 1u)) >> 16;  // RNE
    return (unsigned short)r;
}

// pack 8 fp32 -> 8 bf16 (RNE); compiler emits v_cvt_pk_bf16_f32
__device__ __forceinline__ short8 cvt8(float4 a0, float4 a1) {
    union { __hip_bfloat162 h[4]; short8 v; } u;
    u.h[0] = __float22bfloat162_rn(float2{a0.x, a0.y});
    u.h[1] = __float22bfloat162_rn(float2{a0.z, a0.w});
    u.h[2] = __float22bfloat162_rn(float2{a1.x, a1.y});
    u.h[3] = __float22bfloat162_rn(float2{a1.z, a1.w});
    return u.v;
}

// ---------------- W_en fp32 -> bf16 ----------------
__global__ void wen_convert_kernel(const float* __restrict__ Wen,
                                   unsigned short* __restrict__ Wbf) {
    int idx = blockIdx.x * 256 + threadIdx.x;          // 131072 float4s
    float4 f = ((const float4*)Wen)[idx];
    us4 o = { f2bf(f.x), f2bf(f.y), f2bf(f.z), f2bf(f.w) };
    ((us4*)Wbf)[idx] = o;
}

// ---------------- deproj[b,h] = b_en[h] + sum_t dehy[b,t]*W_de[h,t] ----------------
__global__ void deproj_kernel(const float* __restrict__ dehy,
                              const float* __restrict__ Wde,
                              const float* __restrict__ ben,
                              float* __restrict__ dp) {
    int b = blockIdx.x >> 1;
    int h = ((blockIdx.x & 1) << 8) + threadIdx.x;
    const float4* dv = (const float4*)(dehy + (size_t)b * TRG_);
    const float4* wv = (const float4*)(Wde + (size_t)h * TRG_);
    float s = ben[h];
    #pragma unroll 4
    for (int t = 0; t < TRG_ / 4; ++t) {
        float4 a = dv[t], w = wv[t];
        s += a.x * w.x + a.y * w.y + a.z * w.z + a.w * w.w;
    }
    dp[b * TRG_ + h] = s;
}

// ---------------- fused score GEMM + tanh + w_warp reduce + mask ----------------
// Tile 128(M) x 512(N=all h) x 32(K). 512 thr = 8 waves (2m x 4n); acc 4x8 frags.
// Deep pipeline: A (HBM stream) reg-ring distance 3 (4 static slots, unroll-4);
// B (L2-resident Wbf) 4-deep LDS ring via global_load_lds, staged 2 ahead.
// One s_barrier/step; steady s_waitcnt vmcnt(8) = {A(kt+2), B(kt+1), A(kt+3)} in flight.
__global__ __launch_bounds__(512, 2) void score_kernel(
    const float* __restrict__ enhy,
    const unsigned short* __restrict__ Wbf,
    const float* __restrict__ dp,
    const float* __restrict__ past_attn,
    const int* __restrict__ src_mask,
    const float* __restrict__ w_cv,
    const float* __restrict__ w_warp,
    float* __restrict__ out_ee)
{
    __shared__ unsigned short Bbuf[4][512 * 32];   // 128 KB
    __shared__ unsigned short Abuf[2][128 * 32];   // 16 KB
    __shared__ float red[4][128];                  // 2 KB

    const int tid  = threadIdx.x;
    const int lane = tid & 63;
    const int w    = tid >> 6;
    const int wm   = w >> 2;          // 0..1
    const int wn   = w & 3;           // 0..3
    const int lj   = lane & 15;
    const int lg   = lane >> 4;
    const int m0   = blockIdx.x * 128;
    const int b    = m0 >> 11;
    const int s0   = m0 & 2047;

    // fragment-read 16B-chunk: chunk = lg ^ ((row>>1)&3); 2-way banks (free)
    const int kx = ((lg ^ ((lj >> 1) & 3)) << 4);

    f32x4 acc[4][8];
    const f32x4 fz = {0.f, 0.f, 0.f, 0.f};
    #pragma unroll
    for (int i = 0; i < 4; ++i)
        #pragma unroll
        for (int j = 0; j < 8; ++j) acc[i][j] = fz;

    // A staging: thread -> (row = tid>>2, chunk = tid&3); swizzled LDS dest
    const int arow = tid >> 2;
    const int achk = tid & 3;
    const float* aSrc = enhy + (size_t)(m0 + arow) * K_ + (achk << 3);
    const int aDstByte = arow * 64 + ((achk ^ ((arow >> 1) & 3)) << 4);

    // B staging: pre-swizzled source, linear LDS dest (wave-uniform + lane*16)
    const int brow0 = tid >> 2;
    const int bkc0  = tid & 3;
    const unsigned short* bSrc0 = Wbf + (size_t)brow0 * K_ + ((bkc0 ^ ((brow0 >> 1) & 3)) << 3);
    const int bDst0 = w * 1024;       // bytes; +j*8192 per j-block of 128 rows

#define LOADA(R0, R1, kt) { const float* p_ = aSrc + ((kt) << 5); \
    R0 = *(const float4*)p_; R1 = *(const float4*)(p_ + 4); }
#define WRITEA(asel, R0, R1) { \
    *(short8*)((char*)&Abuf[0][0] + (asel) * 8192 + aDstByte) = cvt8(R0, R1); }
#define STAGEB(bsel, kt) { \
    _Pragma("unroll") \
    for (int j_ = 0; j_ < 4; ++j_) { \
        __builtin_amdgcn_global_load_lds( \
            (const __attribute__((address_space(1))) void*)(bSrc0 + (size_t)j_ * 128 * K_ + ((kt) << 5)), \
            (__attribute__((address_space(3))) void*)((char*)&Bbuf[0][0] + (bsel) * 32768 + bDst0 + j_ * 8192), \
            16, 0, 0); \
    } }
#define WAITS(N) \
    asm volatile("s_waitcnt lgkmcnt(0)" ::: "memory"); \
    asm volatile("s_waitcnt vmcnt(" #N ")" ::: "memory"); \
    __builtin_amdgcn_sched_barrier(0); \
    __builtin_amdgcn_s_barrier(); \
    __builtin_amdgcn_sched_barrier(0);

    auto compute = [&](int bsel, int asel) {
        const char* Bbase = (const char*)&Bbuf[0][0] + bsel * 32768;
        const char* Abase = (const char*)&Abuf[0][0] + asel * 8192;
        short8 bfr[8];
        #pragma unroll
        for (int fn = 0; fn < 8; ++fn) {
            int r = (wn << 7) + (fn << 4) + lj;
            bfr[fn] = *(const short8*)(Bbase + r * 64 + kx);
        }
        __builtin_amdgcn_s_setprio(1);
        #pragma unroll
        for (int fm = 0; fm < 4; ++fm) {
            int rA = (wm << 6) + (fm << 4) + lj;
            short8 af = *(const short8*)(Abase + rA * 64 + kx);
            #pragma unroll
            for (int fn = 0; fn < 8; ++fn)
                acc[fm][fn] = __builtin_amdgcn_mfma_f32_16x16x32_bf16(af, bfr[fn], acc[fm][fn], 0, 0, 0);
        }
        __builtin_amdgcn_s_setprio(0);
    };

    float4 A0a, A0b, A1a, A1b, A2a, A2b, A3a, A3b;

    // ---- prologue: A(0) staged to LDS; B(0),B(1) issued; A(1..3) in ring ----
    LOADA(A0a, A0b, 0);
    WRITEA(0, A0a, A0b);              // compiler auto-waits the two A(0) loads
    STAGEB(0, 0);
    STAGEB(1, 1);
    LOADA(A1a, A1b, 1);
    LOADA(A2a, A2b, 2);
    LOADA(A3a, A3b, 3);

    // ---- steady: kt = 0..27, unroll 4 (slot indices static) ----
    for (int base = 0; base < 28; base += 4) {
        WAITS(8) STAGEB(2, base + 2) LOADA(A0a, A0b, base + 4) WRITEA(1, A1a, A1b) compute(0, 0);
        WAITS(8) STAGEB(3, base + 3) LOADA(A1a, A1b, base + 5) WRITEA(0, A2a, A2b) compute(1, 1);
        WAITS(8) STAGEB(0, base + 4) LOADA(A2a, A2b, base + 6) WRITEA(1, A3a, A3b) compute(2, 0);
        WAITS(8) STAGEB(1, base + 5) LOADA(A3a, A3b, base + 7) WRITEA(0, A0a, A0b) compute(3, 1);
    }
    // ---- tail: kt = 28..31 ----
    WAITS(8) STAGEB(2, 30) WRITEA(1, A1a, A1b) compute(0, 0);   // kt=28
    WAITS(6) STAGEB(3, 31) WRITEA(0, A2a, A2b) compute(1, 1);   // kt=29
    WAITS(4)               WRITEA(1, A3a, A3b) compute(2, 0);   // kt=30
    WAITS(0)                                   compute(3, 1);   // kt=31

#undef LOADA
#undef WRITEA
#undef STAGEB
#undef WAITS

    // ---- epilogue: v=acc+dep+pa*wcv; tanh; *w_warp; reduce over all 512 h ----
    float dep[8], wcv8[8], wwp8[8];
    #pragma unroll
    for (int fn = 0; fn < 8; ++fn) {
        int h = (wn << 7) + (fn << 4) + lj;
        dep[fn]  = dp[b * TRG_ + h];
        wcv8[fn] = w_cv[h];
        wwp8[fn] = w_warp[h];
    }
    #pragma unroll
    for (int fm = 0; fm < 4; ++fm) {
        #pragma unroll
        for (int reg = 0; reg < 4; ++reg) {
            int rloc = (wm << 6) + (fm << 4) + (lg << 2) + reg;
            float pa = past_attn[b * S_ + s0 + rloc];
            float p = 0.f;
            #pragma unroll
            for (int fn = 0; fn < 8; ++fn) {
                float v = acc[fm][fn][reg] + dep[fn] + pa * wcv8[fn];
                float e = __expf(2.f * v);                       // tanh = 1 - 2/(e^{2v}+1)
                float t = 1.f - 2.f * __builtin_amdgcn_rcpf(e + 1.f);
                p += t * wwp8[fn];
            }
            p += __shfl_xor(p, 1);
            p += __shfl_xor(p, 2);
            p += __shfl_xor(p, 4);
            p += __shfl_xor(p, 8);
            if (lj == 0) red[wn][rloc] = p;
        }
    }
    __syncthreads();
    if (tid < 128) {
        float ee = red[0][tid] + red[1][tid] + red[2][tid] + red[3][tid];
        int msk = src_mask[b * S_ + s0 + tid];
        if (msk == 0) ee = -1e20f;
        out_ee[m0 + tid] = ee;
    }
}

// ---------------- softmax over S per batch row ----------------
__global__ void softmax_kernel(const float* __restrict__ ee, float* __restrict__ attn) {
    int b = blockIdx.x, tid = threadIdx.x;   // 256 threads
    const float* row = ee + (size_t)b * S_;
    float v[8]; float mx = -3.0e38f;
    #pragma unroll
    for (int i = 0; i < 8; ++i) { v[i] = row[tid + (i << 8)]; mx = fmaxf(mx, v[i]); }
    #pragma unroll
    for (int off = 32; off > 0; off >>= 1) mx = fmaxf(mx, __shfl_xor(mx, off));
    __shared__ float sred[4];
    int w = tid >> 6, lane = tid & 63;
    if (lane == 0) sred[w] = mx;
    __syncthreads();
    mx = fmaxf(fmaxf(sred[0], sred[1]), fmaxf(sred[2], sred[3]));
    float sum = 0.f;
    #pragma unroll
    for (int i = 0; i < 8; ++i) { v[i] = __expf(v[i] - mx); sum += v[i]; }
    #pragma unroll
    for (int off = 32; off > 0; off >>= 1) sum += __shfl_xor(sum, off);
    __syncthreads();
    if (lane == 0) sred[w] = sum;
    __syncthreads();
    sum = sred[0] + sred[1] + sred[2] + sred[3];
    float inv = 1.f / sum;
    float* orow = attn + (size_t)b * S_;
    #pragma unroll
    for (int i = 0; i < 8; ++i) orow[tid + (i << 8)] = v[i] * inv;
}

// ---------------- context: partial over s-chunks (deterministic) ----------------
__global__ void ctx_partial_kernel(const float* __restrict__ attn,
                                   const float* __restrict__ enhy,
                                   float* __restrict__ part) {
    int bx = blockIdx.x;              // 64*32
    int b = bx >> 5, sc = bx & 31;
    int tid = threadIdx.x;            // 256; each thread one float4 of d
    const float4* e4 = (const float4*)(enhy + ((size_t)b * S_ + sc * 64) * K_);
    const float* ar = attn + (size_t)b * S_ + sc * 64;
    float4 acc = {0.f, 0.f, 0.f, 0.f};
    #pragma unroll 8
    for (int s = 0; s < 64; ++s) {
        float a = ar[s];
        float4 ev = e4[(size_t)s * 256 + tid];
        acc.x += a * ev.x; acc.y += a * ev.y; acc.z += a * ev.z; acc.w += a * ev.w;
    }
    ((float4*)part)[(size_t)(sc * 64 + b) * 256 + tid] = acc;
}

__global__ void ctx_reduce_kernel(const float* __restrict__ part, float* __restrict__ outc) {
    int idx = blockIdx.x * 256 + threadIdx.x;   // 65536
    int b = idx >> 10, d = idx & 1023;
    float s = 0.f;
    #pragma unroll
    for (int sc = 0; sc < 32; ++sc) s += part[(size_t)((sc << 6) + b) * 1024 + d];
    outc[idx] = s;
}

extern "C" void kernel_launch(void* const* d_in, const int* in_sizes, int n_in,
                              void* d_out, int out_size, void* d_ws, size_t ws_size,
                              hipStream_t stream) {
    (void)in_sizes; (void)n_in; (void)out_size; (void)ws_size;

    const float* dehy = (const float*)d_in[0];
    const float* enhy = (const float*)d_in[1];
    const float* past = (const float*)d_in[2];
    const int*   mask = (const int*)d_in[3];
    const float* Wen  = (const float*)d_in[4];
    const float* ben  = (const float*)d_in[5];
    const float* Wde  = (const float*)d_in[6];
    const float* wcv  = (const float*)d_in[7];
    const float* wwp  = (const float*)d_in[8];

    float* out      = (float*)d_out;
    float* out_c    = out;                      // 64*1024
    float* out_attn = out + 65536;              // 64*2048
    float* out_ee   = out + 65536 + 131072;     // 64*2048

    char* ws = (char*)d_ws;
    unsigned short* Wbf = (unsigned short*)ws;              // 1 MB
    float* dp   = (float*)(ws + (1 << 20));                 // 128 KB
    float* part = (float*)(ws + (1 << 20) + (1 << 17));     // 8 MB

    wen_convert_kernel<<<512, 256, 0, stream>>>(Wen, Wbf);
    deproj_kernel<<<128, 256, 0, stream>>>(dehy, Wde, ben, dp);
    score_kernel<<<1024, 512, 0, stream>>>(enhy, Wbf, dp, past, mask, wcv, wwp, out_ee);
    softmax_kernel<<<64, 256, 0, stream>>>(out_ee, out_attn);
    ctx_partial_kernel<<<2048, 256, 0, stream>>>(out_attn, enhy, part);
    ctx_reduce_kernel<<<256, 256, 0, stream>>>(part, out_c);
}